// Round 1
// baseline (1378.659 us; speedup 1.0000x reference)
//
#include <hip/hip_runtime.h>

#define LRELU_ALPHA 0.2f

__device__ __forceinline__ float waveReduceSum(float v) {
#pragma unroll
    for (int off = 32; off > 0; off >>= 1)
        v += __shfl_xor(v, off, 64);
    return v;
}

// vall[k] = sum_o a[o*320+k] * a2[o]   for k in [0,320)
// vall[0:128]=v_src, [128:256]=v_dst, [256:320]=r2
__global__ void k_prep(const float* __restrict__ a, const float* __restrict__ a2,
                       float* __restrict__ vall) {
    int k = blockIdx.x * 64 + threadIdx.x;
    if (k >= 320) return;
    float s = 0.f;
#pragma unroll 8
    for (int o = 0; o < 128; ++o) s += a[o * 320 + k] * a2[o];
    vall[k] = s;
}

// one wave per node: s_src[n] = x[n].v_src, s_dst[n] = x[n].v_dst
__global__ void k_node_scores(const float* __restrict__ x, const float* __restrict__ vall,
                              float* __restrict__ s_src, float* __restrict__ s_dst, int N) {
    int wid = (int)((blockIdx.x * (size_t)blockDim.x + threadIdx.x) >> 6);
    int lane = threadIdx.x & 63;
    if (wid >= N) return;
    const float* xp = x + (size_t)wid * 128;
    float x0 = xp[lane], x1 = xp[lane + 64];
    float ps = x0 * vall[lane] + x1 * vall[lane + 64];
    float pd = x0 * vall[128 + lane] + x1 * vall[192 + lane];
    ps = waveReduceSum(ps);
    pd = waveReduceSum(pd);
    if (lane == 0) { s_src[wid] = ps; s_dst[wid] = pd; }
}

// one wave per edge: score -> edge_e -> atomic scatter into rowsum, u (Nx128), w (Nx64)
__global__ void k_edges(const float* __restrict__ x,
                        const int* __restrict__ e1, int E1,
                        const int* __restrict__ e2, int E2,
                        const float* __restrict__ emb1, const float* __restrict__ emb2,
                        const float* __restrict__ vall,
                        const float* __restrict__ s_src, const float* __restrict__ s_dst,
                        float* __restrict__ rowsum, float* __restrict__ u,
                        float* __restrict__ w) {
    int e = (int)((blockIdx.x * (size_t)blockDim.x + threadIdx.x) >> 6);
    int lane = threadIdx.x & 63;
    int E = E1 + E2;
    if (e >= E) return;
    int src, dst;
    const float* ep;
    if (e < E1) {
        src = e1[e]; dst = e1[E1 + e];
        ep = emb1 + (size_t)e * 64;
    } else {
        int t = e - E1;
        src = e2[t]; dst = e2[E2 + t];
        ep = emb2 + (size_t)t * 64;
    }
    float em = ep[lane];
    float dot = waveReduceSum(em * vall[256 + lane]);
    float score = s_src[src] + s_dst[dst] + dot;
    float p = score > 0.f ? score : LRELU_ALPHA * score;
    float ee = __expf(-p);
    const float* xd = x + (size_t)dst * 128;
    float xv0 = xd[lane], xv1 = xd[lane + 64];
    atomicAdd(&u[(size_t)src * 128 + lane], ee * xv0);
    atomicAdd(&u[(size_t)src * 128 + 64 + lane], ee * xv1);
    atomicAdd(&w[(size_t)src * 64 + lane], ee * em);
    if (lane == 0) atomicAdd(&rowsum[src], ee);
}

// per-node scales: sx = rowsum/rsc (1 or 0), inv = 1/rsc
__global__ void k_scales(const float* __restrict__ rowsum, float* __restrict__ sx,
                         float* __restrict__ inv, int N) {
    int n = blockIdx.x * blockDim.x + threadIdx.x;
    if (n >= N) return;
    float rs = rowsum[n];
    float rsc = (rs == 0.f) ? 1e-12f : rs;
    inv[n] = 1.f / rsc;
    sx[n] = rs / rsc;
}

// out[n][o] = elu( sum_k G[n][k]*a[o][k] ),
// G[n] = [ x[n]*sx[n] (128) | u[n]*inv[n] (128) | w[n]*inv[n] (64) ]
// tile: 32 nodes x 128 o per block of 256 threads; K-chunks of 64.
__global__ __launch_bounds__(256) void k_out(
    const float* __restrict__ x, const float* __restrict__ u,
    const float* __restrict__ w, const float* __restrict__ sx,
    const float* __restrict__ inv, const float* __restrict__ a,
    float* __restrict__ out, int N) {
    __shared__ float At[128][68];  // row stride 68 floats = 272B (16B aligned)
    __shared__ float Gt[32][68];
    int tid = threadIdx.x;
    int n0 = blockIdx.x * 32;
    int tn = tid >> 5;   // 0..7  -> nodes tn*4 .. tn*4+3
    int to = tid & 31;   // 0..31 -> outputs to*4 .. to*4+3
    float acc[4][4] = {{0.f}};

    for (int c = 0; c < 5; ++c) {
        // load A tile: 128 x 64
#pragma unroll
        for (int i = 0; i < 32; ++i) {
            int idx = tid + i * 256;
            int o = idx >> 6, kk = idx & 63;
            At[o][kk] = a[o * 320 + c * 64 + kk];
        }
        // load G tile: 32 x 64 (computed on the fly)
#pragma unroll
        for (int i = 0; i < 8; ++i) {
            int idx = tid + i * 256;
            int nl = idx >> 6, kk = idx & 63;
            int n = n0 + nl;
            float v = 0.f;
            if (n < N) {
                if (c < 2)       v = x[(size_t)n * 128 + c * 64 + kk] * sx[n];
                else if (c < 4)  v = u[(size_t)n * 128 + (c - 2) * 64 + kk] * inv[n];
                else             v = w[(size_t)n * 64 + kk] * inv[n];
            }
            Gt[nl][kk] = v;
        }
        __syncthreads();
#pragma unroll
        for (int kk = 0; kk < 64; kk += 4) {
            float4 g[4], av[4];
#pragma unroll
            for (int j = 0; j < 4; ++j)
                g[j] = *reinterpret_cast<const float4*>(&Gt[tn * 4 + j][kk]);
#pragma unroll
            for (int j = 0; j < 4; ++j)
                av[j] = *reinterpret_cast<const float4*>(&At[to * 4 + j][kk]);
#pragma unroll
            for (int j = 0; j < 4; ++j)
#pragma unroll
                for (int l = 0; l < 4; ++l) {
                    acc[j][l] += g[j].x * av[l].x;
                    acc[j][l] += g[j].y * av[l].y;
                    acc[j][l] += g[j].z * av[l].z;
                    acc[j][l] += g[j].w * av[l].w;
                }
        }
        __syncthreads();
    }

#pragma unroll
    for (int j = 0; j < 4; ++j) {
        int n = n0 + tn * 4 + j;
        if (n >= N) continue;
        float4 o4;
        float h0 = acc[j][0], h1 = acc[j][1], h2 = acc[j][2], h3 = acc[j][3];
        o4.x = h0 > 0.f ? h0 : (__expf(h0) - 1.f);
        o4.y = h1 > 0.f ? h1 : (__expf(h1) - 1.f);
        o4.z = h2 > 0.f ? h2 : (__expf(h2) - 1.f);
        o4.w = h3 > 0.f ? h3 : (__expf(h3) - 1.f);
        *reinterpret_cast<float4*>(&out[(size_t)n * 128 + to * 4]) = o4;
    }
}

extern "C" void kernel_launch(void* const* d_in, const int* in_sizes, int n_in,
                              void* d_out, int out_size, void* d_ws, size_t ws_size,
                              hipStream_t stream) {
    const float* x    = (const float*)d_in[0];
    const int*   e1   = (const int*)d_in[1];
    const float* emb1 = (const float*)d_in[2];
    const int*   e2   = (const int*)d_in[3];
    const float* emb2 = (const float*)d_in[4];
    const float* a    = (const float*)d_in[5];
    const float* a2   = (const float*)d_in[6];
    float* out = (float*)d_out;

    const int N  = in_sizes[0] / 128;
    const int E1 = in_sizes[1] / 2;
    const int E2 = in_sizes[3] / 2;
    const int E  = E1 + E2;

    // workspace layout (floats)
    float* ws     = (float*)d_ws;
    float* vall   = ws;                 // 320 (padded to 512)
    float* s_src  = ws + 512;           // N
    float* s_dst  = s_src + N;          // N
    float* sx     = s_dst + N;          // N
    float* inv    = sx + N;             // N
    float* rowsum = inv + N;            // N     -- zeroed region starts here
    float* u      = rowsum + N;         // N*128
    float* w      = u + (size_t)N * 128;// N*64
    size_t needed = (512 + (size_t)N * 197) * sizeof(float);
    if (ws_size < needed) return;  // defensive; should not happen

    hipMemsetAsync(rowsum, 0, (size_t)N * 193 * sizeof(float), stream);

    k_prep<<<5, 64, 0, stream>>>(a, a2, vall);
    k_node_scores<<<(N * 64 + 255) / 256, 256, 0, stream>>>(x, vall, s_src, s_dst, N);
    k_edges<<<((size_t)E * 64 + 255) / 256, 256, 0, stream>>>(
        x, e1, E1, e2, E2, emb1, emb2, vall, s_src, s_dst, rowsum, u, w);
    k_scales<<<(N + 255) / 256, 256, 0, stream>>>(rowsum, sx, inv, N);
    k_out<<<(N + 31) / 32, 256, 0, stream>>>(x, u, w, sx, inv, a, out, N);
}

// Round 2
// 864.192 us; speedup vs baseline: 1.5953x; 1.5953x over previous
//
#include <hip/hip_runtime.h>
#include <hip/hip_bf16.h>

#define LRELU_ALPHA 0.2f

__device__ __forceinline__ float waveReduceSum(float v) {
#pragma unroll
    for (int off = 32; off > 0; off >>= 1)
        v += __shfl_xor(v, off, 64);
    return v;
}

// vall[k] = sum_o a[o*320+k] * a2[o]; [0:128]=v_src, [128:256]=v_dst, [256:320]=r2
__global__ void k_prep(const float* __restrict__ a, const float* __restrict__ a2,
                       float* __restrict__ vall) {
    int k = blockIdx.x * 64 + threadIdx.x;
    if (k >= 320) return;
    float s = 0.f;
#pragma unroll 8
    for (int o = 0; o < 128; ++o) s += a[o * 320 + k] * a2[o];
    vall[k] = s;
}

// At[k][o] = a[o][k]  (320 x 128)
__global__ void k_at(const float* __restrict__ a, float* __restrict__ At) {
    int idx = blockIdx.x * blockDim.x + threadIdx.x;
    if (idx >= 128 * 320) return;
    int o = idx / 320, k = idx - o * 320;
    At[k * 128 + o] = a[idx];
}

// one wave per node: s_src[n] = x[n].v_src, s_dst[n] = x[n].v_dst
__global__ void k_node_scores(const float* __restrict__ x, const float* __restrict__ vall,
                              float* __restrict__ s_src, float* __restrict__ s_dst, int N) {
    int wid = (int)((blockIdx.x * (size_t)blockDim.x + threadIdx.x) >> 6);
    int lane = threadIdx.x & 63;
    if (wid >= N) return;
    const float* xp = x + (size_t)wid * 128;
    float x0 = xp[lane], x1 = xp[lane + 64];
    float ps = x0 * vall[lane] + x1 * vall[lane + 64];
    float pd = x0 * vall[128 + lane] + x1 * vall[192 + lane];
    ps = waveReduceSum(ps);
    pd = waveReduceSum(pd);
    if (lane == 0) { s_src[wid] = ps; s_dst[wid] = pd; }
}

__global__ void k_count(const int* __restrict__ e1, int E1, const int* __restrict__ e2, int E2,
                        int* __restrict__ cnt) {
    int e = blockIdx.x * blockDim.x + threadIdx.x;
    if (e >= E1 + E2) return;
    int src = (e < E1) ? e1[e] : e2[e - E1];
    atomicAdd(&cnt[src], 1);
}

// single-block exclusive scan of cnt[N] -> start[N+1], cursor[N]
__global__ __launch_bounds__(1024) void k_scan(const int* __restrict__ cnt, int* __restrict__ start,
                                               int* __restrict__ cursor, int N, int E) {
    __shared__ int part[1024];
    int t = threadIdx.x;
    int C = (N + 1023) >> 10;
    int b0 = t * C;
    int s = 0;
    for (int i = 0; i < C; ++i) {
        int idx = b0 + i;
        if (idx < N) s += cnt[idx];
    }
    part[t] = s;
    __syncthreads();
    for (int off = 1; off < 1024; off <<= 1) {
        int add = (t >= off) ? part[t - off] : 0;
        __syncthreads();
        part[t] += add;
        __syncthreads();
    }
    int run = part[t] - s;  // exclusive prefix of this thread's range
    for (int i = 0; i < C; ++i) {
        int idx = b0 + i;
        if (idx < N) { start[idx] = run; cursor[idx] = run; run += cnt[idx]; }
    }
    if (t == 1023) start[N] = E;
}

// bucket edges by src: se[p] = (dst, e)
__global__ void k_scatter(const int* __restrict__ e1, int E1, const int* __restrict__ e2, int E2,
                          int* __restrict__ cursor, int2* __restrict__ se) {
    int e = blockIdx.x * blockDim.x + threadIdx.x;
    if (e >= E1 + E2) return;
    int src, dst;
    if (e < E1) { src = e1[e]; dst = e1[E1 + e]; }
    else { int t = e - E1; src = e2[t]; dst = e2[E2 + t]; }
    int p = atomicAdd(&cursor[src], 1);
    se[p] = make_int2(dst, e);
}

// one wave per node: accumulate u, w, rowsum in registers; no atomics.
// writes UW[n] = [u*inv (128) | w*inv (64)] in bf16, sx[n] = (rowsum>0)
__global__ void k_gather(const float* __restrict__ x,
                         const float* __restrict__ emb1, const float* __restrict__ emb2, int E1,
                         const int* __restrict__ start, const int2* __restrict__ se,
                         const float* __restrict__ vall,
                         const float* __restrict__ s_src, const float* __restrict__ s_dst,
                         __hip_bfloat16* __restrict__ UW, float* __restrict__ sx, int N) {
    int n = (int)((blockIdx.x * (size_t)blockDim.x + threadIdx.x) >> 6);
    int lane = threadIdx.x & 63;
    if (n >= N) return;
    int b = start[n], en = start[n + 1];
    float r2l = vall[256 + lane];
    float ssrc = s_src[n];
    float u0 = 0.f, u1 = 0.f, w0 = 0.f, rs = 0.f;
    for (int p = b; p < en; ++p) {
        int2 de = se[p];
        int dst = de.x, e = de.y;
        const float* ep = (e < E1) ? emb1 + (size_t)e * 64 : emb2 + (size_t)(e - E1) * 64;
        float em = ep[lane];
        const float* xd = x + (size_t)dst * 128;
        float xv0 = xd[lane], xv1 = xd[lane + 64];
        float sd = s_dst[dst];
        float dot = waveReduceSum(em * r2l);
        float score = ssrc + sd + dot;
        float pz = score > 0.f ? score : LRELU_ALPHA * score;
        float ee = __expf(-pz);
        u0 += ee * xv0; u1 += ee * xv1; w0 += ee * em; rs += ee;
    }
    float inv = (rs == 0.f) ? 0.f : 1.f / rs;
    __hip_bfloat16* uwp = UW + (size_t)n * 192;
    uwp[lane]       = __float2bfloat16(u0 * inv);
    uwp[64 + lane]  = __float2bfloat16(u1 * inv);
    uwp[128 + lane] = __float2bfloat16(w0 * inv);
    if (lane == 0) sx[n] = (rs == 0.f) ? 0.f : 1.f;
}

// out[n][o] = elu( sum_k G[n][k] * At[k][o] )
// G[n] = [x[n]*sx (128) | UW[n] (192, bf16)]
// block: 64 nodes x 128 o, 256 threads; At read from global (L2-resident),
// G chunk staged in LDS (node-major, broadcast reads).
__global__ __launch_bounds__(256) void k_out(
    const float* __restrict__ x, const __hip_bfloat16* __restrict__ UW,
    const float* __restrict__ sx, const float* __restrict__ At,
    float* __restrict__ out, int N) {
    __shared__ float Gs[64][68];
    int tid = threadIdx.x;
    int n0 = blockIdx.x * 64;
    int to = tid & 31;   // o-quad: outputs 4*to .. 4*to+3
    int tn = tid >> 5;   // node group: nodes tn*8 .. tn*8+7
    float acc[8][4];
#pragma unroll
    for (int j = 0; j < 8; ++j)
#pragma unroll
        for (int l = 0; l < 4; ++l) acc[j][l] = 0.f;

    for (int c = 0; c < 5; ++c) {
        // stage 64 nodes x 64 k of G
#pragma unroll
        for (int i = 0; i < 16; ++i) {
            int idx = i * 256 + tid;
            int nl = idx >> 6, kk = idx & 63;
            int n = n0 + nl;
            float v = 0.f;
            if (n < N) {
                if (c < 2) v = x[(size_t)n * 128 + c * 64 + kk] * sx[n];
                else       v = __bfloat162float(UW[(size_t)n * 192 + (c - 2) * 64 + kk]);
            }
            Gs[nl][kk] = v;
        }
        __syncthreads();
        const float* Ab = At + (size_t)c * 64 * 128;
#pragma unroll 2
        for (int k4 = 0; k4 < 16; ++k4) {
            float4 av[4];
#pragma unroll
            for (int q = 0; q < 4; ++q)
                av[q] = *reinterpret_cast<const float4*>(&Ab[(size_t)(k4 * 4 + q) * 128 + to * 4]);
            float4 g[8];
#pragma unroll
            for (int j = 0; j < 8; ++j)
                g[j] = *reinterpret_cast<const float4*>(&Gs[tn * 8 + j][k4 * 4]);
#pragma unroll
            for (int j = 0; j < 8; ++j) {
#pragma unroll
                for (int l = 0; l < 4; ++l) {
                    float* al = &acc[j][l];
                    float a0 = (&av[0].x)[l], a1 = (&av[1].x)[l], a2 = (&av[2].x)[l], a3 = (&av[3].x)[l];
                    *al += g[j].x * a0;
                    *al += g[j].y * a1;
                    *al += g[j].z * a2;
                    *al += g[j].w * a3;
                }
            }
        }
        __syncthreads();
    }

#pragma unroll
    for (int j = 0; j < 8; ++j) {
        int n = n0 + tn * 8 + j;
        if (n >= N) continue;
        float4 o4;
        float h0 = acc[j][0], h1 = acc[j][1], h2 = acc[j][2], h3 = acc[j][3];
        o4.x = h0 > 0.f ? h0 : (__expf(h0) - 1.f);
        o4.y = h1 > 0.f ? h1 : (__expf(h1) - 1.f);
        o4.z = h2 > 0.f ? h2 : (__expf(h2) - 1.f);
        o4.w = h3 > 0.f ? h3 : (__expf(h3) - 1.f);
        *reinterpret_cast<float4*>(&out[(size_t)n * 128 + to * 4]) = o4;
    }
}

extern "C" void kernel_launch(void* const* d_in, const int* in_sizes, int n_in,
                              void* d_out, int out_size, void* d_ws, size_t ws_size,
                              hipStream_t stream) {
    const float* x    = (const float*)d_in[0];
    const int*   e1   = (const int*)d_in[1];
    const float* emb1 = (const float*)d_in[2];
    const int*   e2   = (const int*)d_in[3];
    const float* emb2 = (const float*)d_in[4];
    const float* a    = (const float*)d_in[5];
    const float* a2   = (const float*)d_in[6];
    float* out = (float*)d_out;

    const int N  = in_sizes[0] / 128;
    const int E1 = in_sizes[1] / 2;
    const int E2 = in_sizes[3] / 2;
    const int E  = E1 + E2;

    // workspace layout
    float* ws    = (float*)d_ws;
    float* vall  = ws;                    // 512
    float* s_src = ws + 512;              // N
    float* s_dst = s_src + N;             // N
    float* sx    = s_dst + N;             // N
    float* At    = sx + N;                // 320*128
    int*   cnt    = (int*)(At + 320 * 128);  // N
    int*   start  = cnt + N;                 // N+1
    int*   cursor = start + N + 1;           // N
    int2*  se     = (int2*)(cursor + N + 1); // E int2 (pad keeps 8B alignment)
    __hip_bfloat16* UW = (__hip_bfloat16*)(se + E); // 192*N bf16

    size_t needed = (char*)(UW + (size_t)N * 192) - (char*)d_ws;
    if (ws_size < needed) return;  // defensive

    hipMemsetAsync(cnt, 0, (size_t)N * sizeof(int), stream);

    k_prep<<<5, 64, 0, stream>>>(a, a2, vall);
    k_at<<<(128 * 320 + 255) / 256, 256, 0, stream>>>(a, At);
    k_node_scores<<<(N * 64 + 255) / 256, 256, 0, stream>>>(x, vall, s_src, s_dst, N);
    k_count<<<(E + 255) / 256, 256, 0, stream>>>(e1, E1, e2, E2, cnt);
    k_scan<<<1, 1024, 0, stream>>>(cnt, start, cursor, N, E);
    k_scatter<<<(E + 255) / 256, 256, 0, stream>>>(e1, E1, e2, E2, cursor, se);
    k_gather<<<(N * 64 + 255) / 256, 256, 0, stream>>>(
        x, emb1, emb2, E1, start, se, vall, s_src, s_dst, UW, sx, N);
    k_out<<<(N + 63) / 64, 256, 0, stream>>>(x, UW, sx, At, out, N);
}

// Round 3
// 692.299 us; speedup vs baseline: 1.9914x; 1.2483x over previous
//
#include <hip/hip_runtime.h>
#include <hip/hip_bf16.h>

#define LRELU_ALPHA 0.2f

__device__ __forceinline__ float waveReduceSum(float v) {
#pragma unroll
    for (int off = 32; off > 0; off >>= 1)
        v += __shfl_xor(v, off, 64);
    return v;
}

// vall[k] = sum_o a[o*320+k] * a2[o]; [0:128]=v_src, [128:256]=v_dst, [256:320]=r2
__global__ void k_prep(const float* __restrict__ a, const float* __restrict__ a2,
                       float* __restrict__ vall) {
    int k = blockIdx.x * 64 + threadIdx.x;
    if (k >= 320) return;
    float s = 0.f;
#pragma unroll 8
    for (int o = 0; o < 128; ++o) s += a[o * 320 + k] * a2[o];
    vall[k] = s;
}

// At[k][o] = a[o][k]  (320 x 128)
__global__ void k_at(const float* __restrict__ a, float* __restrict__ At) {
    int idx = blockIdx.x * blockDim.x + threadIdx.x;
    if (idx >= 128 * 320) return;
    int o = idx / 320, k = idx - o * 320;
    At[k * 128 + o] = a[idx];
}

// one wave per node: s_src[n] = x[n].v_src, s_dst[n] = x[n].v_dst
__global__ void k_node_scores(const float* __restrict__ x, const float* __restrict__ vall,
                              float* __restrict__ s_src, float* __restrict__ s_dst, int N) {
    int wid = (int)((blockIdx.x * (size_t)blockDim.x + threadIdx.x) >> 6);
    int lane = threadIdx.x & 63;
    if (wid >= N) return;
    const float* xp = x + (size_t)wid * 128;
    float x0 = xp[lane], x1 = xp[lane + 64];
    float ps = x0 * vall[lane] + x1 * vall[lane + 64];
    float pd = x0 * vall[128 + lane] + x1 * vall[192 + lane];
    ps = waveReduceSum(ps);
    pd = waveReduceSum(pd);
    if (lane == 0) { s_src[wid] = ps; s_dst[wid] = pd; }
}

// streaming edge-score pass: 4 edges per wave, 16 lanes (float4) per edge.
// ee[e] = exp(-leakyrelu(s_src[src]+s_dst[dst]+emb[e].r2)); also counts cnt[src].
__global__ void k_escore(const int* __restrict__ e1, int E1,
                         const int* __restrict__ e2, int E2,
                         const float* __restrict__ emb1, const float* __restrict__ emb2,
                         const float* __restrict__ vall,
                         const float* __restrict__ s_src, const float* __restrict__ s_dst,
                         float* __restrict__ ee, int* __restrict__ cnt) {
    int gid = blockIdx.x * blockDim.x + threadIdx.x;
    int wave = gid >> 6;
    int lane = threadIdx.x & 63;
    int g = lane >> 4, s = lane & 15;
    int e = wave * 4 + g;
    int E = E1 + E2;
    if (e >= E) return;
    const float* ep = (e < E1) ? emb1 + (size_t)e * 64 : emb2 + (size_t)(e - E1) * 64;
    float4 v = *reinterpret_cast<const float4*>(ep + s * 4);
    float4 r = *reinterpret_cast<const float4*>(vall + 256 + s * 4);
    float d = v.x * r.x + v.y * r.y + v.z * r.z + v.w * r.w;
    d += __shfl_xor(d, 1, 64);
    d += __shfl_xor(d, 2, 64);
    d += __shfl_xor(d, 4, 64);
    d += __shfl_xor(d, 8, 64);
    if (s == 0) {
        int src, dst;
        if (e < E1) { src = e1[e]; dst = e1[E1 + e]; }
        else { int t = e - E1; src = e2[t]; dst = e2[E2 + t]; }
        float score = s_src[src] + s_dst[dst] + d;
        float pz = score > 0.f ? score : LRELU_ALPHA * score;
        ee[e] = __expf(-pz);
        atomicAdd(&cnt[src], 1);
    }
}

// hierarchical exclusive scan of cnt[N] -> start[N+1], cursor[N]
__global__ void k_scan1(const int* __restrict__ cnt, int* __restrict__ bsum, int N) {
    __shared__ int red[256];
    int t = threadIdx.x;
    int idx = blockIdx.x * 256 + t;
    red[t] = (idx < N) ? cnt[idx] : 0;
    __syncthreads();
    for (int off = 128; off > 0; off >>= 1) {
        if (t < off) red[t] += red[t + off];
        __syncthreads();
    }
    if (t == 0) bsum[blockIdx.x] = red[0];
}

__global__ void k_scan2(int* __restrict__ bsum, int nb) {
    __shared__ int tmp[256];
    int t = threadIdx.x;
    int v = (t < nb) ? bsum[t] : 0;
    tmp[t] = v;
    __syncthreads();
    for (int off = 1; off < 256; off <<= 1) {
        int add = (t >= off) ? tmp[t - off] : 0;
        __syncthreads();
        tmp[t] += add;
        __syncthreads();
    }
    if (t < nb) bsum[t] = tmp[t] - v;  // exclusive
}

__global__ void k_scan3(const int* __restrict__ cnt, const int* __restrict__ bsum,
                        int* __restrict__ start, int* __restrict__ cursor, int N, int E) {
    __shared__ int tmp[256];
    int t = threadIdx.x;
    int idx = blockIdx.x * 256 + t;
    int v = (idx < N) ? cnt[idx] : 0;
    tmp[t] = v;
    __syncthreads();
    for (int off = 1; off < 256; off <<= 1) {
        int add = (t >= off) ? tmp[t - off] : 0;
        __syncthreads();
        tmp[t] += add;
        __syncthreads();
    }
    if (idx < N) {
        int excl = tmp[t] - v + bsum[blockIdx.x];
        start[idx] = excl;
        cursor[idx] = excl;
    }
    if (blockIdx.x == 0 && t == 0) start[N] = E;
}

// bucket edges by src: se[p] = (dst, e)
__global__ void k_scatter(const int* __restrict__ e1, int E1, const int* __restrict__ e2, int E2,
                          int* __restrict__ cursor, int2* __restrict__ se) {
    int e = blockIdx.x * blockDim.x + threadIdx.x;
    if (e >= E1 + E2) return;
    int src, dst;
    if (e < E1) { src = e1[e]; dst = e1[E1 + e]; }
    else { int t = e - E1; src = e2[t]; dst = e2[E2 + t]; }
    int p = atomicAdd(&cursor[src], 1);
    se[p] = make_int2(dst, e);
}

// one wave per node: accumulate u, w, rowsum with precomputed ee; no cross-lane ops.
// writes UW[n] = [u*inv (128) | w*inv (64)] in bf16, sx[n] = (rowsum>0)
__global__ void k_gather(const float* __restrict__ x,
                         const float* __restrict__ emb1, const float* __restrict__ emb2, int E1,
                         const int* __restrict__ start, const int2* __restrict__ se,
                         const float* __restrict__ eetab,
                         __hip_bfloat16* __restrict__ UW, float* __restrict__ sx, int N) {
    int n = (int)((blockIdx.x * (size_t)blockDim.x + threadIdx.x) >> 6);
    int lane = threadIdx.x & 63;
    if (n >= N) return;
    n = __builtin_amdgcn_readfirstlane(n);
    int b = start[n], en = start[n + 1];
    float u0 = 0.f, u1 = 0.f, w0 = 0.f, rs = 0.f;
    int p = b;
    for (; p + 1 < en; p += 2) {
        int2 d0 = se[p];
        int2 d1 = se[p + 1];
        float ee0 = eetab[d0.y];
        float ee1 = eetab[d1.y];
        const float* ep0 = (d0.y < E1) ? emb1 + (size_t)d0.y * 64 : emb2 + (size_t)(d0.y - E1) * 64;
        const float* ep1 = (d1.y < E1) ? emb1 + (size_t)d1.y * 64 : emb2 + (size_t)(d1.y - E1) * 64;
        const float* x0 = x + (size_t)d0.x * 128;
        const float* x1 = x + (size_t)d1.x * 128;
        float em0 = ep0[lane], em1 = ep1[lane];
        float a0 = x0[lane], a1 = x0[lane + 64];
        float b0 = x1[lane], b1 = x1[lane + 64];
        u0 += ee0 * a0; u1 += ee0 * a1; w0 += ee0 * em0; rs += ee0;
        u0 += ee1 * b0; u1 += ee1 * b1; w0 += ee1 * em1; rs += ee1;
    }
    if (p < en) {
        int2 d0 = se[p];
        float ee0 = eetab[d0.y];
        const float* ep0 = (d0.y < E1) ? emb1 + (size_t)d0.y * 64 : emb2 + (size_t)(d0.y - E1) * 64;
        const float* x0 = x + (size_t)d0.x * 128;
        u0 += ee0 * x0[lane]; u1 += ee0 * x0[lane + 64]; w0 += ee0 * ep0[lane]; rs += ee0;
    }
    float inv = (rs == 0.f) ? 0.f : 1.f / rs;
    __hip_bfloat16* uwp = UW + (size_t)n * 192;
    uwp[lane]       = __float2bfloat16(u0 * inv);
    uwp[64 + lane]  = __float2bfloat16(u1 * inv);
    uwp[128 + lane] = __float2bfloat16(w0 * inv);
    if (lane == 0) sx[n] = (rs == 0.f) ? 0.f : 1.f;
}

// out[n][o] = elu( sum_k G[n][k] * At[k][o] )
// G[n] = [x[n]*sx (128) | UW[n] (192, bf16)]
__global__ __launch_bounds__(256) void k_out(
    const float* __restrict__ x, const __hip_bfloat16* __restrict__ UW,
    const float* __restrict__ sx, const float* __restrict__ At,
    float* __restrict__ out, int N) {
    __shared__ float Gs[64][68];
    int tid = threadIdx.x;
    int n0 = blockIdx.x * 64;
    int to = tid & 31;   // o-quad: outputs 4*to .. 4*to+3
    int tn = tid >> 5;   // node group: nodes tn*8 .. tn*8+7
    float acc[8][4];
#pragma unroll
    for (int j = 0; j < 8; ++j)
#pragma unroll
        for (int l = 0; l < 4; ++l) acc[j][l] = 0.f;

    for (int c = 0; c < 5; ++c) {
#pragma unroll
        for (int i = 0; i < 16; ++i) {
            int idx = i * 256 + tid;
            int nl = idx >> 6, kk = idx & 63;
            int n = n0 + nl;
            float v = 0.f;
            if (n < N) {
                if (c < 2) v = x[(size_t)n * 128 + c * 64 + kk] * sx[n];
                else       v = __bfloat162float(UW[(size_t)n * 192 + (c - 2) * 64 + kk]);
            }
            Gs[nl][kk] = v;
        }
        __syncthreads();
        const float* Ab = At + (size_t)c * 64 * 128;
#pragma unroll 2
        for (int k4 = 0; k4 < 16; ++k4) {
            float4 av[4];
#pragma unroll
            for (int q = 0; q < 4; ++q)
                av[q] = *reinterpret_cast<const float4*>(&Ab[(size_t)(k4 * 4 + q) * 128 + to * 4]);
            float4 g[8];
#pragma unroll
            for (int j = 0; j < 8; ++j)
                g[j] = *reinterpret_cast<const float4*>(&Gs[tn * 8 + j][k4 * 4]);
#pragma unroll
            for (int j = 0; j < 8; ++j) {
#pragma unroll
                for (int l = 0; l < 4; ++l) {
                    float* al = &acc[j][l];
                    *al += g[j].x * (&av[0].x)[l];
                    *al += g[j].y * (&av[1].x)[l];
                    *al += g[j].z * (&av[2].x)[l];
                    *al += g[j].w * (&av[3].x)[l];
                }
            }
        }
        __syncthreads();
    }

#pragma unroll
    for (int j = 0; j < 8; ++j) {
        int n = n0 + tn * 8 + j;
        if (n >= N) continue;
        float4 o4;
        float h0 = acc[j][0], h1 = acc[j][1], h2 = acc[j][2], h3 = acc[j][3];
        o4.x = h0 > 0.f ? h0 : (__expf(h0) - 1.f);
        o4.y = h1 > 0.f ? h1 : (__expf(h1) - 1.f);
        o4.z = h2 > 0.f ? h2 : (__expf(h2) - 1.f);
        o4.w = h3 > 0.f ? h3 : (__expf(h3) - 1.f);
        *reinterpret_cast<float4*>(&out[(size_t)n * 128 + to * 4]) = o4;
    }
}

extern "C" void kernel_launch(void* const* d_in, const int* in_sizes, int n_in,
                              void* d_out, int out_size, void* d_ws, size_t ws_size,
                              hipStream_t stream) {
    const float* x    = (const float*)d_in[0];
    const int*   e1   = (const int*)d_in[1];
    const float* emb1 = (const float*)d_in[2];
    const int*   e2   = (const int*)d_in[3];
    const float* emb2 = (const float*)d_in[4];
    const float* a    = (const float*)d_in[5];
    const float* a2   = (const float*)d_in[6];
    float* out = (float*)d_out;

    const int N  = in_sizes[0] / 128;
    const int E1 = in_sizes[1] / 2;
    const int E2 = in_sizes[3] / 2;
    const int E  = E1 + E2;
    const int NB = (N + 255) / 256;  // scan blocks (<=256 assumed: N<=65536)

    // workspace layout (floats)
    float* ws    = (float*)d_ws;
    float* vall  = ws;                     // 512
    float* s_src = ws + 512;               // N
    float* s_dst = s_src + N;              // N
    float* sx    = s_dst + N;              // N
    float* At    = sx + N;                 // 320*128
    int*   cnt    = (int*)(At + 320 * 128);   // N
    int*   bsum   = cnt + N;                  // 256
    int*   start  = bsum + 256;               // N+1
    int*   cursor = start + N + 1;            // N+1 (pad to even)
    float* ee     = (float*)(cursor + N + 1); // E
    size_t ee_off = (size_t)(ee - ws);
    if (ee_off & 1) ee += 1;                  // keep following int2 8B-aligned
    int2*  se     = (int2*)(ee + E);          // E int2
    __hip_bfloat16* UW = (__hip_bfloat16*)(se + E); // 192*N bf16

    size_t needed = (char*)(UW + (size_t)N * 192) - (char*)d_ws;
    if (ws_size < needed) return;  // defensive

    hipMemsetAsync(cnt, 0, (size_t)N * sizeof(int), stream);

    k_prep<<<5, 64, 0, stream>>>(a, a2, vall);
    k_at<<<(128 * 320 + 255) / 256, 256, 0, stream>>>(a, At);
    k_node_scores<<<(N * 64 + 255) / 256, 256, 0, stream>>>(x, vall, s_src, s_dst, N);
    {
        long long waves = ((long long)E + 3) / 4;
        long long blocks = (waves * 64 + 255) / 256;
        k_escore<<<(int)blocks, 256, 0, stream>>>(e1, E1, e2, E2, emb1, emb2,
                                                  vall, s_src, s_dst, ee, cnt);
    }
    k_scan1<<<NB, 256, 0, stream>>>(cnt, bsum, N);
    k_scan2<<<1, 256, 0, stream>>>(bsum, NB);
    k_scan3<<<NB, 256, 0, stream>>>(cnt, bsum, start, cursor, N, E);
    k_scatter<<<(E + 255) / 256, 256, 0, stream>>>(e1, E1, e2, E2, cursor, se);
    k_gather<<<(N * 64 + 255) / 256, 256, 0, stream>>>(
        x, emb1, emb2, E1, start, se, ee, UW, sx, N);
    k_out<<<(N + 63) / 64, 256, 0, stream>>>(x, UW, sx, At, out, N);
}

// Round 4
// 608.233 us; speedup vs baseline: 2.2667x; 1.1382x over previous
//
#include <hip/hip_runtime.h>
#include <hip/hip_bf16.h>

#define LRELU_ALPHA 0.2f

typedef __bf16 bf16x8 __attribute__((ext_vector_type(8)));
typedef float f32x4 __attribute__((ext_vector_type(4)));

__device__ __forceinline__ float waveReduceSum(float v) {
#pragma unroll
    for (int off = 32; off > 0; off >>= 1)
        v += __shfl_xor(v, off, 64);
    return v;
}

// vall[k] = sum_o a[o*320+k]*a2[o]  (k<320); ABf = bf16(a) (128x320 row-major)
__global__ void k_prep(const float* __restrict__ a, const float* __restrict__ a2,
                       float* __restrict__ vall, __hip_bfloat16* __restrict__ ABf) {
    int idx = blockIdx.x * 256 + threadIdx.x;
    if (idx < 128 * 320) ABf[idx] = __float2bfloat16(a[idx]);
    if (idx < 320) {
        float s = 0.f;
#pragma unroll 8
        for (int o = 0; o < 128; ++o) s += a[o * 320 + idx] * a2[o];
        vall[idx] = s;
    }
}

// one wave per node: s_src[n] = x[n].v_src, s_dst[n] = x[n].v_dst
__global__ void k_node_scores(const float* __restrict__ x, const float* __restrict__ vall,
                              float* __restrict__ s_src, float* __restrict__ s_dst, int N) {
    int wid = (int)((blockIdx.x * (size_t)blockDim.x + threadIdx.x) >> 6);
    int lane = threadIdx.x & 63;
    if (wid >= N) return;
    const float* xp = x + (size_t)wid * 128;
    float x0 = xp[lane], x1 = xp[lane + 64];
    float ps = x0 * vall[lane] + x1 * vall[lane + 64];
    float pd = x0 * vall[128 + lane] + x1 * vall[192 + lane];
    ps = waveReduceSum(ps);
    pd = waveReduceSum(pd);
    if (lane == 0) { s_src[wid] = ps; s_dst[wid] = pd; }
}

// streaming edge-score pass: 4 edges per wave, 16 lanes (float4) per edge.
__global__ void k_escore(const int* __restrict__ e1, int E1,
                         const int* __restrict__ e2, int E2,
                         const float* __restrict__ emb1, const float* __restrict__ emb2,
                         const float* __restrict__ vall,
                         const float* __restrict__ s_src, const float* __restrict__ s_dst,
                         float* __restrict__ ee, int* __restrict__ cnt) {
    int gid = blockIdx.x * blockDim.x + threadIdx.x;
    int wave = gid >> 6;
    int lane = threadIdx.x & 63;
    int g = lane >> 4, s = lane & 15;
    int e = wave * 4 + g;
    int E = E1 + E2;
    if (e >= E) return;
    const float* ep = (e < E1) ? emb1 + (size_t)e * 64 : emb2 + (size_t)(e - E1) * 64;
    float4 v = *reinterpret_cast<const float4*>(ep + s * 4);
    float4 r = *reinterpret_cast<const float4*>(vall + 256 + s * 4);
    float d = v.x * r.x + v.y * r.y + v.z * r.z + v.w * r.w;
    d += __shfl_xor(d, 1, 64);
    d += __shfl_xor(d, 2, 64);
    d += __shfl_xor(d, 4, 64);
    d += __shfl_xor(d, 8, 64);
    if (s == 0) {
        int src, dst;
        if (e < E1) { src = e1[e]; dst = e1[E1 + e]; }
        else { int t = e - E1; src = e2[t]; dst = e2[E2 + t]; }
        float score = s_src[src] + s_dst[dst] + d;
        float pz = score > 0.f ? score : LRELU_ALPHA * score;
        ee[e] = __expf(-pz);
        atomicAdd(&cnt[src], 1);
    }
}

// hierarchical exclusive scan of cnt[N] -> start[N+1], cursor[N]
__global__ void k_scan1(const int* __restrict__ cnt, int* __restrict__ bsum, int N) {
    __shared__ int red[256];
    int t = threadIdx.x;
    int idx = blockIdx.x * 256 + t;
    red[t] = (idx < N) ? cnt[idx] : 0;
    __syncthreads();
    for (int off = 128; off > 0; off >>= 1) {
        if (t < off) red[t] += red[t + off];
        __syncthreads();
    }
    if (t == 0) bsum[blockIdx.x] = red[0];
}

__global__ void k_scan2(int* __restrict__ bsum, int nb) {
    __shared__ int tmp[256];
    int t = threadIdx.x;
    int v = (t < nb) ? bsum[t] : 0;
    tmp[t] = v;
    __syncthreads();
    for (int off = 1; off < 256; off <<= 1) {
        int add = (t >= off) ? tmp[t - off] : 0;
        __syncthreads();
        tmp[t] += add;
        __syncthreads();
    }
    if (t < nb) bsum[t] = tmp[t] - v;  // exclusive
}

__global__ void k_scan3(const int* __restrict__ cnt, const int* __restrict__ bsum,
                        int* __restrict__ start, int* __restrict__ cursor, int N, int E) {
    __shared__ int tmp[256];
    int t = threadIdx.x;
    int idx = blockIdx.x * 256 + t;
    int v = (idx < N) ? cnt[idx] : 0;
    tmp[t] = v;
    __syncthreads();
    for (int off = 1; off < 256; off <<= 1) {
        int add = (t >= off) ? tmp[t - off] : 0;
        __syncthreads();
        tmp[t] += add;
        __syncthreads();
    }
    if (idx < N) {
        int excl = tmp[t] - v + bsum[blockIdx.x];
        start[idx] = excl;
        cursor[idx] = excl;
    }
    if (blockIdx.x == 0 && t == 0) start[N] = E;
}

// bucket edges by src: se[p] = (dst, e)
__global__ void k_scatter(const int* __restrict__ e1, int E1, const int* __restrict__ e2, int E2,
                          int* __restrict__ cursor, int2* __restrict__ se) {
    int e = blockIdx.x * blockDim.x + threadIdx.x;
    if (e >= E1 + E2) return;
    int src, dst;
    if (e < E1) { src = e1[e]; dst = e1[E1 + e]; }
    else { int t = e - E1; src = e2[t]; dst = e2[E2 + t]; }
    int p = atomicAdd(&cursor[src], 1);
    se[p] = make_int2(dst, e);
}

// one wave per node, unroll x4: G[n] = [u*inv (128) | w*inv (64)] bf16; sxf[n]=rowsum>0
__global__ void k_gather(const float* __restrict__ x,
                         const float* __restrict__ emb1, const float* __restrict__ emb2, int E1,
                         const int* __restrict__ start, const int2* __restrict__ se,
                         const float* __restrict__ eetab,
                         __hip_bfloat16* __restrict__ G, float* __restrict__ sxf, int N) {
    int n = (int)((blockIdx.x * (size_t)blockDim.x + threadIdx.x) >> 6);
    int lane = threadIdx.x & 63;
    if (n >= N) return;
    n = __builtin_amdgcn_readfirstlane(n);
    int b = start[n], en = start[n + 1];
    float ux = 0.f, uy = 0.f, w0 = 0.f, rs = 0.f;
    int p = b;
    for (; p + 3 < en; p += 4) {
        int2 d0 = se[p], d1 = se[p + 1], d2 = se[p + 2], d3 = se[p + 3];
        float e0 = eetab[d0.y], e1v = eetab[d1.y], e2v = eetab[d2.y], e3v = eetab[d3.y];
        const float* ep0 = (d0.y < E1) ? emb1 + (size_t)d0.y * 64 : emb2 + (size_t)(d0.y - E1) * 64;
        const float* ep1 = (d1.y < E1) ? emb1 + (size_t)d1.y * 64 : emb2 + (size_t)(d1.y - E1) * 64;
        const float* ep2 = (d2.y < E1) ? emb1 + (size_t)d2.y * 64 : emb2 + (size_t)(d2.y - E1) * 64;
        const float* ep3 = (d3.y < E1) ? emb1 + (size_t)d3.y * 64 : emb2 + (size_t)(d3.y - E1) * 64;
        float2 xv0 = *reinterpret_cast<const float2*>(x + (size_t)d0.x * 128 + 2 * lane);
        float2 xv1 = *reinterpret_cast<const float2*>(x + (size_t)d1.x * 128 + 2 * lane);
        float2 xv2 = *reinterpret_cast<const float2*>(x + (size_t)d2.x * 128 + 2 * lane);
        float2 xv3 = *reinterpret_cast<const float2*>(x + (size_t)d3.x * 128 + 2 * lane);
        float em0 = ep0[lane], em1 = ep1[lane], em2 = ep2[lane], em3 = ep3[lane];
        ux += e0 * xv0.x; uy += e0 * xv0.y; w0 += e0 * em0; rs += e0;
        ux += e1v * xv1.x; uy += e1v * xv1.y; w0 += e1v * em1; rs += e1v;
        ux += e2v * xv2.x; uy += e2v * xv2.y; w0 += e2v * em2; rs += e2v;
        ux += e3v * xv3.x; uy += e3v * xv3.y; w0 += e3v * em3; rs += e3v;
    }
    for (; p < en; ++p) {
        int2 d0 = se[p];
        float e0 = eetab[d0.y];
        const float* ep0 = (d0.y < E1) ? emb1 + (size_t)d0.y * 64 : emb2 + (size_t)(d0.y - E1) * 64;
        float2 xv0 = *reinterpret_cast<const float2*>(x + (size_t)d0.x * 128 + 2 * lane);
        ux += e0 * xv0.x; uy += e0 * xv0.y; w0 += e0 * ep0[lane]; rs += e0;
    }
    float inv = (rs == 0.f) ? 0.f : 1.f / rs;
    __hip_bfloat16* gp = G + (size_t)n * 192;
    __hip_bfloat162 uv;
    uv.x = __float2bfloat16(ux * inv);
    uv.y = __float2bfloat16(uy * inv);
    *reinterpret_cast<__hip_bfloat162*>(gp + 2 * lane) = uv;
    gp[128 + lane] = __float2bfloat16(w0 * inv);
    if (lane == 0) sxf[n] = (rs == 0.f) ? 0.f : 1.f;
}

// out[n][o] = elu( sxf[n] * (x[n].a_src[o] + G[n].[a_dst|a_rel][o]) ) via bf16 MFMA.
// wave = 16 rows x 128 cols; A-frag k<128 from fp32 x (cvt), k>=128 from G bf16;
// B-frag from ABf (a row-major: B[k][o] = a[o][k], contiguous per lane).
__global__ __launch_bounds__(256) void k_mfma(
    const float* __restrict__ x, const __hip_bfloat16* __restrict__ G,
    const __hip_bfloat16* __restrict__ ABf, const float* __restrict__ sxf,
    float* __restrict__ out, int N) {
    int lane = threadIdx.x & 63;
    int wave = threadIdx.x >> 6;
    int m0 = blockIdx.x * 64 + wave * 16;
    int q = lane >> 4, m = lane & 15;
    int rowm = m0 + m; if (rowm >= N) rowm = N - 1;  // clamp; garbage rows never stored
    const float* xr = x + (size_t)rowm * 128 + q * 8;
    const __hip_bfloat16* gr = G + (size_t)rowm * 192 + q * 8;
    const __hip_bfloat16* br = ABf + (size_t)m * 320 + q * 8;
    f32x4 acc[8];
#pragma unroll
    for (int c = 0; c < 8; ++c) acc[c] = f32x4{0.f, 0.f, 0.f, 0.f};

#pragma unroll
    for (int s = 0; s < 4; ++s) {  // k = s*32 .. +32 from x
        float4 xa = *reinterpret_cast<const float4*>(xr + s * 32);
        float4 xb = *reinterpret_cast<const float4*>(xr + s * 32 + 4);
        bf16x8 af;
        af[0] = (__bf16)xa.x; af[1] = (__bf16)xa.y; af[2] = (__bf16)xa.z; af[3] = (__bf16)xa.w;
        af[4] = (__bf16)xb.x; af[5] = (__bf16)xb.y; af[6] = (__bf16)xb.z; af[7] = (__bf16)xb.w;
#pragma unroll
        for (int c = 0; c < 8; ++c) {
            bf16x8 bf = *reinterpret_cast<const bf16x8*>(br + (size_t)c * 16 * 320 + s * 32);
            acc[c] = __builtin_amdgcn_mfma_f32_16x16x32_bf16(af, bf, acc[c], 0, 0, 0);
        }
    }
#pragma unroll
    for (int s = 0; s < 6; ++s) {  // k = 128 + s*32 .. +32 from G
        bf16x8 af = *reinterpret_cast<const bf16x8*>(gr + s * 32);
#pragma unroll
        for (int c = 0; c < 8; ++c) {
            bf16x8 bf = *reinterpret_cast<const bf16x8*>(br + (size_t)c * 16 * 320 + 128 + s * 32);
            acc[c] = __builtin_amdgcn_mfma_f32_16x16x32_bf16(af, bf, acc[c], 0, 0, 0);
        }
    }

    float sxr[4];
#pragma unroll
    for (int r = 0; r < 4; ++r) {
        int n = m0 + q * 4 + r;
        sxr[r] = (n < N) ? sxf[n] : 0.f;
    }
#pragma unroll
    for (int c = 0; c < 8; ++c) {
#pragma unroll
        for (int r = 0; r < 4; ++r) {
            int n = m0 + q * 4 + r;
            if (n < N) {
                float h = acc[c][r] * sxr[r];
                out[(size_t)n * 128 + c * 16 + m] = h > 0.f ? h : __expf(h) - 1.f;
            }
        }
    }
}

extern "C" void kernel_launch(void* const* d_in, const int* in_sizes, int n_in,
                              void* d_out, int out_size, void* d_ws, size_t ws_size,
                              hipStream_t stream) {
    const float* x    = (const float*)d_in[0];
    const int*   e1   = (const int*)d_in[1];
    const float* emb1 = (const float*)d_in[2];
    const int*   e2   = (const int*)d_in[3];
    const float* emb2 = (const float*)d_in[4];
    const float* a    = (const float*)d_in[5];
    const float* a2   = (const float*)d_in[6];
    float* out = (float*)d_out;

    const int N  = in_sizes[0] / 128;
    const int E1 = in_sizes[1] / 2;
    const int E2 = in_sizes[3] / 2;
    const int E  = E1 + E2;
    const int NB = (N + 255) / 256;  // <=256 (N<=65536)

    // workspace layout
    float* ws    = (float*)d_ws;
    float* vall  = ws;                                   // 512 f
    __hip_bfloat16* ABf = (__hip_bfloat16*)(ws + 512);   // 128*320 bf16 = 20480 f
    float* s_src = ws + 512 + 20480;                     // N
    float* s_dst = s_src + N;                            // N
    float* sxf   = s_dst + N;                            // N
    int*   cnt    = (int*)(sxf + N);                     // N
    int*   bsum   = cnt + N;                             // 256
    int*   start  = bsum + 256;                          // N+1
    int*   cursor = start + N + 1;                       // N+1
    float* ee     = (float*)(cursor + N + 1);            // E
    if ((size_t)(ee - ws) & 1) ee += 1;                  // 8B align for int2
    int2*  se     = (int2*)(ee + E);                     // E int2
    size_t go = (size_t)((char*)(se + E) - (char*)d_ws);
    go = (go + 15) & ~(size_t)15;                        // 16B align for bf16x8 loads
    __hip_bfloat16* G = (__hip_bfloat16*)((char*)d_ws + go);  // N*192 bf16

    size_t needed = go + (size_t)N * 192 * sizeof(__hip_bfloat16);
    if (ws_size < needed) return;  // defensive

    hipMemsetAsync(cnt, 0, (size_t)N * sizeof(int), stream);

    k_prep<<<(128 * 320 + 255) / 256, 256, 0, stream>>>(a, a2, vall, ABf);
    k_node_scores<<<(N * 64 + 255) / 256, 256, 0, stream>>>(x, vall, s_src, s_dst, N);
    {
        long long waves = ((long long)E + 3) / 4;
        long long blocks = (waves * 64 + 255) / 256;
        k_escore<<<(int)blocks, 256, 0, stream>>>(e1, E1, e2, E2, emb1, emb2,
                                                  vall, s_src, s_dst, ee, cnt);
    }
    k_scan1<<<NB, 256, 0, stream>>>(cnt, bsum, N);
    k_scan2<<<1, 256, 0, stream>>>(bsum, NB);
    k_scan3<<<NB, 256, 0, stream>>>(cnt, bsum, start, cursor, N, E);
    k_scatter<<<(E + 255) / 256, 256, 0, stream>>>(e1, E1, e2, E2, cursor, se);
    k_gather<<<(N * 64 + 255) / 256, 256, 0, stream>>>(
        x, emb1, emb2, E1, start, se, ee, G, sxf, N);
    k_mfma<<<(N + 63) / 64, 256, 0, stream>>>(x, G, ABf, sxf, out, N);
}

// Round 5
// 565.177 us; speedup vs baseline: 2.4393x; 1.0762x over previous
//
#include <hip/hip_runtime.h>
#include <hip/hip_bf16.h>

#define LRELU_ALPHA 0.2f

typedef __bf16 bf16x8 __attribute__((ext_vector_type(8)));
typedef float f32x4 __attribute__((ext_vector_type(4)));

__device__ __forceinline__ float waveReduceSum(float v) {
#pragma unroll
    for (int off = 32; off > 0; off >>= 1)
        v += __shfl_xor(v, off, 64);
    return v;
}

// vall[k] = sum_o a[o*320+k]*a2[o]  (k<320); ABf = bf16(a) (128x320 row-major)
__global__ void k_prep(const float* __restrict__ a, const float* __restrict__ a2,
                       float* __restrict__ vall, __hip_bfloat16* __restrict__ ABf) {
    int idx = blockIdx.x * 256 + threadIdx.x;
    if (idx < 128 * 320) ABf[idx] = __float2bfloat16(a[idx]);
    if (idx < 320) {
        float s = 0.f;
#pragma unroll 8
        for (int o = 0; o < 128; ++o) s += a[o * 320 + idx] * a2[o];
        vall[idx] = s;
    }
}

// one wave per node: s_src/s_dst dots; also writes bf16 copy of x (XBf)
__global__ void k_node_scores(const float* __restrict__ x, const float* __restrict__ vall,
                              float* __restrict__ s_src, float* __restrict__ s_dst,
                              __hip_bfloat16* __restrict__ XBf, int N) {
    int wid = (int)((blockIdx.x * (size_t)blockDim.x + threadIdx.x) >> 6);
    int lane = threadIdx.x & 63;
    if (wid >= N) return;
    const float* xp = x + (size_t)wid * 128;
    float x0 = xp[lane], x1 = xp[lane + 64];
    XBf[(size_t)wid * 128 + lane]      = __float2bfloat16(x0);
    XBf[(size_t)wid * 128 + 64 + lane] = __float2bfloat16(x1);
    float ps = x0 * vall[lane] + x1 * vall[lane + 64];
    float pd = x0 * vall[128 + lane] + x1 * vall[192 + lane];
    ps = waveReduceSum(ps);
    pd = waveReduceSum(pd);
    if (lane == 0) { s_src[wid] = ps; s_dst[wid] = pd; }
}

__global__ void k_count(const int* __restrict__ e1, int E1, const int* __restrict__ e2, int E2,
                        int* __restrict__ cnt) {
    int e = blockIdx.x * blockDim.x + threadIdx.x;
    if (e >= E1 + E2) return;
    int src = (e < E1) ? e1[e] : e2[e - E1];
    atomicAdd(&cnt[src], 1);
}

// hierarchical exclusive scan of cnt[N] -> start[N+1], cursor[N]
__global__ void k_scan1(const int* __restrict__ cnt, int* __restrict__ bsum, int N) {
    __shared__ int red[256];
    int t = threadIdx.x;
    int idx = blockIdx.x * 256 + t;
    red[t] = (idx < N) ? cnt[idx] : 0;
    __syncthreads();
    for (int off = 128; off > 0; off >>= 1) {
        if (t < off) red[t] += red[t + off];
        __syncthreads();
    }
    if (t == 0) bsum[blockIdx.x] = red[0];
}

__global__ void k_scan2(int* __restrict__ bsum, int nb) {
    __shared__ int tmp[256];
    int t = threadIdx.x;
    int v = (t < nb) ? bsum[t] : 0;
    tmp[t] = v;
    __syncthreads();
    for (int off = 1; off < 256; off <<= 1) {
        int add = (t >= off) ? tmp[t - off] : 0;
        __syncthreads();
        tmp[t] += add;
        __syncthreads();
    }
    if (t < nb) bsum[t] = tmp[t] - v;  // exclusive
}

__global__ void k_scan3(const int* __restrict__ cnt, const int* __restrict__ bsum,
                        int* __restrict__ start, int* __restrict__ cursor, int N, int E) {
    __shared__ int tmp[256];
    int t = threadIdx.x;
    int idx = blockIdx.x * 256 + t;
    int v = (idx < N) ? cnt[idx] : 0;
    tmp[t] = v;
    __syncthreads();
    for (int off = 1; off < 256; off <<= 1) {
        int add = (t >= off) ? tmp[t - off] : 0;
        __syncthreads();
        tmp[t] += add;
        __syncthreads();
    }
    if (idx < N) {
        int excl = tmp[t] - v + bsum[blockIdx.x];
        start[idx] = excl;
        cursor[idx] = excl;
    }
    if (blockIdx.x == 0 && t == 0) start[N] = E;
}

// bucket edges by src: se[p] = (dst, e)
__global__ void k_scatter(const int* __restrict__ e1, int E1, const int* __restrict__ e2, int E2,
                          int* __restrict__ cursor, int2* __restrict__ se) {
    int e = blockIdx.x * blockDim.x + threadIdx.x;
    if (e >= E1 + E2) return;
    int src, dst;
    if (e < E1) { src = e1[e]; dst = e1[E1 + e]; }
    else { int t = e - E1; src = e2[t]; dst = e2[E2 + t]; }
    int p = atomicAdd(&cursor[src], 1);
    se[p] = make_int2(dst, e);
}

// one wave per node, FUSED: reads emb once, computes score+exp inline,
// accumulates u (bf16 x), w, rowsum. Writes G[n] = [u*inv | w*inv] bf16, sxf.
__global__ void k_gather(const __hip_bfloat16* __restrict__ XBf,
                         const float* __restrict__ emb1, const float* __restrict__ emb2, int E1,
                         const int* __restrict__ start, const int2* __restrict__ se,
                         const float* __restrict__ vall,
                         const float* __restrict__ s_src, const float* __restrict__ s_dst,
                         __hip_bfloat16* __restrict__ G, float* __restrict__ sxf, int N) {
    int n = (int)((blockIdx.x * (size_t)blockDim.x + threadIdx.x) >> 6);
    int lane = threadIdx.x & 63;
    if (n >= N) return;
    n = __builtin_amdgcn_readfirstlane(n);
    int b = start[n], en = start[n + 1];
    float r2l = vall[256 + lane];
    float ssrc = s_src[n];
    float ux = 0.f, uy = 0.f, w0 = 0.f, rs = 0.f;
    int p = b;
    for (; p + 1 < en; p += 2) {
        int2 d0 = se[p], d1 = se[p + 1];
        const float* ep0 = (d0.y < E1) ? emb1 + (size_t)d0.y * 64 : emb2 + (size_t)(d0.y - E1) * 64;
        const float* ep1 = (d1.y < E1) ? emb1 + (size_t)d1.y * 64 : emb2 + (size_t)(d1.y - E1) * 64;
        float em0 = ep0[lane], em1 = ep1[lane];
        __hip_bfloat162 xv0 = *reinterpret_cast<const __hip_bfloat162*>(XBf + (size_t)d0.x * 128 + 2 * lane);
        __hip_bfloat162 xv1 = *reinterpret_cast<const __hip_bfloat162*>(XBf + (size_t)d1.x * 128 + 2 * lane);
        float sd0 = s_dst[d0.x], sd1 = s_dst[d1.x];
        float t0 = em0 * r2l, t1 = em1 * r2l;
#pragma unroll
        for (int off = 32; off > 0; off >>= 1) {
            t0 += __shfl_xor(t0, off, 64);
            t1 += __shfl_xor(t1, off, 64);
        }
        float sc0 = ssrc + sd0 + t0;
        float sc1 = ssrc + sd1 + t1;
        float pz0 = sc0 > 0.f ? sc0 : LRELU_ALPHA * sc0;
        float pz1 = sc1 > 0.f ? sc1 : LRELU_ALPHA * sc1;
        float e0 = __expf(-pz0), e1v = __expf(-pz1);
        ux += e0 * __bfloat162float(xv0.x); uy += e0 * __bfloat162float(xv0.y);
        w0 += e0 * em0; rs += e0;
        ux += e1v * __bfloat162float(xv1.x); uy += e1v * __bfloat162float(xv1.y);
        w0 += e1v * em1; rs += e1v;
    }
    if (p < en) {
        int2 d0 = se[p];
        const float* ep0 = (d0.y < E1) ? emb1 + (size_t)d0.y * 64 : emb2 + (size_t)(d0.y - E1) * 64;
        float em0 = ep0[lane];
        __hip_bfloat162 xv0 = *reinterpret_cast<const __hip_bfloat162*>(XBf + (size_t)d0.x * 128 + 2 * lane);
        float sd0 = s_dst[d0.x];
        float t0 = waveReduceSum(em0 * r2l);
        float sc0 = ssrc + sd0 + t0;
        float pz0 = sc0 > 0.f ? sc0 : LRELU_ALPHA * sc0;
        float e0 = __expf(-pz0);
        ux += e0 * __bfloat162float(xv0.x); uy += e0 * __bfloat162float(xv0.y);
        w0 += e0 * em0; rs += e0;
    }
    float inv = (rs == 0.f) ? 0.f : 1.f / rs;
    __hip_bfloat16* gp = G + (size_t)n * 192;
    __hip_bfloat162 uv;
    uv.x = __float2bfloat16(ux * inv);
    uv.y = __float2bfloat16(uy * inv);
    *reinterpret_cast<__hip_bfloat162*>(gp + 2 * lane) = uv;
    gp[128 + lane] = __float2bfloat16(w0 * inv);
    if (lane == 0) sxf[n] = (rs == 0.f) ? 0.f : 1.f;
}

// out[n][o] = elu( sxf[n] * (x[n].a_src[o] + G[n].[a_dst|a_rel][o]) ) via bf16 MFMA.
__global__ __launch_bounds__(256) void k_mfma(
    const __hip_bfloat16* __restrict__ XBf, const __hip_bfloat16* __restrict__ G,
    const __hip_bfloat16* __restrict__ ABf, const float* __restrict__ sxf,
    float* __restrict__ out, int N) {
    int lane = threadIdx.x & 63;
    int wave = threadIdx.x >> 6;
    int m0 = blockIdx.x * 64 + wave * 16;
    int q = lane >> 4, m = lane & 15;
    int rowm = m0 + m; if (rowm >= N) rowm = N - 1;  // clamp; garbage rows never stored
    const __hip_bfloat16* xr = XBf + (size_t)rowm * 128 + q * 8;
    const __hip_bfloat16* gr = G + (size_t)rowm * 192 + q * 8;
    const __hip_bfloat16* br = ABf + (size_t)m * 320 + q * 8;
    f32x4 acc[8];
#pragma unroll
    for (int c = 0; c < 8; ++c) acc[c] = f32x4{0.f, 0.f, 0.f, 0.f};

#pragma unroll
    for (int s = 0; s < 4; ++s) {  // k = s*32 .. +32 from XBf
        bf16x8 af = *reinterpret_cast<const bf16x8*>(xr + s * 32);
#pragma unroll
        for (int c = 0; c < 8; ++c) {
            bf16x8 bf = *reinterpret_cast<const bf16x8*>(br + (size_t)c * 16 * 320 + s * 32);
            acc[c] = __builtin_amdgcn_mfma_f32_16x16x32_bf16(af, bf, acc[c], 0, 0, 0);
        }
    }
#pragma unroll
    for (int s = 0; s < 6; ++s) {  // k = 128 + s*32 .. +32 from G
        bf16x8 af = *reinterpret_cast<const bf16x8*>(gr + s * 32);
#pragma unroll
        for (int c = 0; c < 8; ++c) {
            bf16x8 bf = *reinterpret_cast<const bf16x8*>(br + (size_t)c * 16 * 320 + 128 + s * 32);
            acc[c] = __builtin_amdgcn_mfma_f32_16x16x32_bf16(af, bf, acc[c], 0, 0, 0);
        }
    }

    float sxr[4];
#pragma unroll
    for (int r = 0; r < 4; ++r) {
        int n = m0 + q * 4 + r;
        sxr[r] = (n < N) ? sxf[n] : 0.f;
    }
#pragma unroll
    for (int c = 0; c < 8; ++c) {
#pragma unroll
        for (int r = 0; r < 4; ++r) {
            int n = m0 + q * 4 + r;
            if (n < N) {
                float h = acc[c][r] * sxr[r];
                out[(size_t)n * 128 + c * 16 + m] = h > 0.f ? h : __expf(h) - 1.f;
            }
        }
    }
}

extern "C" void kernel_launch(void* const* d_in, const int* in_sizes, int n_in,
                              void* d_out, int out_size, void* d_ws, size_t ws_size,
                              hipStream_t stream) {
    const float* x    = (const float*)d_in[0];
    const int*   e1   = (const int*)d_in[1];
    const float* emb1 = (const float*)d_in[2];
    const int*   e2   = (const int*)d_in[3];
    const float* emb2 = (const float*)d_in[4];
    const float* a    = (const float*)d_in[5];
    const float* a2   = (const float*)d_in[6];
    float* out = (float*)d_out;

    const int N  = in_sizes[0] / 128;
    const int E1 = in_sizes[1] / 2;
    const int E2 = in_sizes[3] / 2;
    const int E  = E1 + E2;
    const int NB = (N + 255) / 256;  // <=256 (N<=65536)

    // workspace layout
    float* ws    = (float*)d_ws;
    float* vall  = ws;                                   // 512 f
    __hip_bfloat16* ABf = (__hip_bfloat16*)(ws + 512);   // 128*320 bf16 = 20480 f
    float* s_src = ws + 512 + 20480;                     // N
    float* s_dst = s_src + N;                            // N
    float* sxf   = s_dst + N;                            // N
    int*   cnt    = (int*)(sxf + N);                     // N
    int*   bsum   = cnt + N;                             // 256
    int*   start  = bsum + 256;                          // N+1
    int*   cursor = start + N + 1;                       // N+1
    size_t so = (size_t)((char*)(cursor + N + 1) - (char*)d_ws);
    so = (so + 15) & ~(size_t)15;
    int2*  se = (int2*)((char*)d_ws + so);               // E int2
    size_t xo = so + (size_t)E * sizeof(int2);
    xo = (xo + 15) & ~(size_t)15;
    __hip_bfloat16* XBf = (__hip_bfloat16*)((char*)d_ws + xo);  // N*128 bf16
    size_t go = xo + (size_t)N * 128 * sizeof(__hip_bfloat16);
    go = (go + 15) & ~(size_t)15;
    __hip_bfloat16* G = (__hip_bfloat16*)((char*)d_ws + go);    // N*192 bf16

    size_t needed = go + (size_t)N * 192 * sizeof(__hip_bfloat16);
    if (ws_size < needed) return;  // defensive

    hipMemsetAsync(cnt, 0, (size_t)N * sizeof(int), stream);

    k_prep<<<(128 * 320 + 255) / 256, 256, 0, stream>>>(a, a2, vall, ABf);
    k_node_scores<<<(N * 64 + 255) / 256, 256, 0, stream>>>(x, vall, s_src, s_dst, XBf, N);
    k_count<<<(E + 255) / 256, 256, 0, stream>>>(e1, E1, e2, E2, cnt);
    k_scan1<<<NB, 256, 0, stream>>>(cnt, bsum, N);
    k_scan2<<<1, 256, 0, stream>>>(bsum, NB);
    k_scan3<<<NB, 256, 0, stream>>>(cnt, bsum, start, cursor, N, E);
    k_scatter<<<(E + 255) / 256, 256, 0, stream>>>(e1, E1, e2, E2, cursor, se);
    k_gather<<<(N * 64 + 255) / 256, 256, 0, stream>>>(
        XBf, emb1, emb2, E1, start, se, vall, s_src, s_dst, G, sxf, N);
    k_mfma<<<(N + 63) / 64, 256, 0, stream>>>(XBf, G, ABf, sxf, out, N);
}